// Round 1
// 79.711 us; speedup vs baseline: 1.0835x; 1.0835x over previous
//
#include <hip/hip_runtime.h>

#define NN 100000
#define DIN 128
#define DOUT 64
#define NE 1600000

#define BSHIFT 6
#define BROWS 64             // rows per bucket
#define NB 1563              // ceil(100000/64)
#define CAP 1536             // slots/bucket; mean 1024, sigma 32 -> +16 sigma
#define EPB 8192             // edges per place-block (196 blocks)

// ---------------- ws layout (bytes) ----------------
#define XWB_B  0u                            // ushort[NN*DOUT] = 12.8 MB
#define GCUR_B 12800000u                     // int[NB] (padded to 8 KB)
#define BPAD_B (GCUR_B + 8192u)              // int2[NB*CAP] = 19.2 MB
#define WS_NEED (BPAD_B + (unsigned)NB * CAP * 8u)   // ~32.0 MB

typedef unsigned short u16;
typedef unsigned int u32;
typedef __attribute__((ext_vector_type(8))) short v8s;   // 8 bf16 = 4 VGPR
typedef __attribute__((ext_vector_type(4))) float v4f;   // MFMA acc

__device__ __forceinline__ float bf2f(u16 u) {
  return __uint_as_float(((u32)u) << 16);
}
__device__ __forceinline__ u16 f2bf(float f) {
  u32 x = __float_as_uint(f);
  u32 r = x + 0x7fffu + ((x >> 16) & 1u);
  return (u16)(r >> 16);
}

// ---------------------------------------------------------------------------
// GEMM v7 (validated r13: ~10-12 us real): W fragments staged ONCE per block
// into LDS (16 KB, fragment-order), waves read via ds_read_b128. Per 16-row
// tile: 8 float4 x-loads -> 4 A-frags -> 16x mfma_f32_16x16x32_bf16.
// ---------------------------------------------------------------------------
__global__ __launch_bounds__(256) void gemm_kernel(
    const float* __restrict__ x, const float* __restrict__ w,
    u16* __restrict__ xwb) {
  __shared__ u16 wlds[16 * 64 * 8];   // 16 KB
  const int t = threadIdx.x;
  const int lane = t & 63;
  const int wv = t >> 6;

  #pragma unroll
  for (int pi = 0; pi < 4; ++pi) {
    const int p = t * 4 + pi;
    const int f = p >> 6, lp = p & 63;
    const int kc = f >> 2, nc = f & 3;
    const int kg = lp >> 4, lr = lp & 15;
    const int kbase = kc * 32 + kg * 8;
    u32 pk[4];
    #pragma unroll
    for (int h = 0; h < 4; ++h) {
      const u32 lo = f2bf(w[(kbase + 2 * h)     * DOUT + nc * 16 + lr]);
      const u32 hi = f2bf(w[(kbase + 2 * h + 1) * DOUT + nc * 16 + lr]);
      pk[h] = lo | (hi << 16);
    }
    *reinterpret_cast<uint4*>(&wlds[p * 8]) =
        make_uint4(pk[0], pk[1], pk[2], pk[3]);
  }
  __syncthreads();

  const int row0 = blockIdx.x * 64 + wv * 16;
  if (row0 >= NN) return;            // safe: after the only barrier
  const int lrow = lane & 15;
  const int lkg  = lane >> 4;

  v8s Bf[4][4];
  #pragma unroll
  for (int kc = 0; kc < 4; ++kc)
    #pragma unroll
    for (int nc = 0; nc < 4; ++nc)
      Bf[kc][nc] = *reinterpret_cast<const v8s*>(
          &wlds[((kc * 4 + nc) * 64 + lane) * 8]);

  const float* xr = x + (size_t)(row0 + lrow) * DIN + lkg * 8;
  float4 xa[4][2];
  #pragma unroll
  for (int kc = 0; kc < 4; ++kc) {
    xa[kc][0] = *reinterpret_cast<const float4*>(xr + kc * 32);
    xa[kc][1] = *reinterpret_cast<const float4*>(xr + kc * 32 + 4);
  }

  v4f acc[4];
  #pragma unroll
  for (int nc = 0; nc < 4; ++nc) acc[nc] = (v4f){0.f, 0.f, 0.f, 0.f};

  #pragma unroll
  for (int kc = 0; kc < 4; ++kc) {
    v8s Af;
    Af[0] = (short)f2bf(xa[kc][0].x);
    Af[1] = (short)f2bf(xa[kc][0].y);
    Af[2] = (short)f2bf(xa[kc][0].z);
    Af[3] = (short)f2bf(xa[kc][0].w);
    Af[4] = (short)f2bf(xa[kc][1].x);
    Af[5] = (short)f2bf(xa[kc][1].y);
    Af[6] = (short)f2bf(xa[kc][1].z);
    Af[7] = (short)f2bf(xa[kc][1].w);
    #pragma unroll
    for (int nc = 0; nc < 4; ++nc)
      acc[nc] = __builtin_amdgcn_mfma_f32_16x16x32_bf16(Af, Bf[kc][nc],
                                                        acc[nc], 0, 0, 0);
  }

  #pragma unroll
  for (int nc = 0; nc < 4; ++nc)
    #pragma unroll
    for (int j = 0; j < 4; ++j)
      xwb[(size_t)(row0 + lkg * 4 + j) * DOUT + nc * 16 + lrow] =
          f2bf(acc[nc][j]);
}

// ---------------------------------------------------------------------------
// place v2: SAME 196 blocks / claim count, but 1024 threads (16 waves) ->
// per-thread serial chains halve, occupancy 12% -> ~38%.
// Payload: q.x = (row&63)<<17 | col, q.y = val bits.
// ---------------------------------------------------------------------------
__global__ __launch_bounds__(1024) void place_kernel(
    const int* __restrict__ erow, const int* __restrict__ ecol,
    const float* __restrict__ eval_, int* __restrict__ gcur,
    int2* __restrict__ bpad) {
  __shared__ int hist[NB];
  __shared__ int base[NB];
  __shared__ int lcur[NB];
  const int t = threadIdx.x;
  for (int i = t; i < NB; i += 1024) { hist[i] = 0; lcur[i] = 0; }
  __syncthreads();

  const int e0 = blockIdx.x * EPB;
  const int e1 = min(e0 + EPB, NE);
  for (int e = e0 + t; e < e1; e += 1024)
    atomicAdd(&hist[erow[e] >> BSHIFT], 1);
  __syncthreads();

  for (int i = t; i < NB; i += 1024) {
    const int h = hist[i];
    base[i] = h ? atomicAdd(&gcur[i], h) : 0;   // one claim per touched bucket
  }
  __syncthreads();

  for (int e = e0 + t; e < e1; e += 1024) {
    const int r = erow[e];
    const int b = r >> BSHIFT;
    const int rank = base[b] + atomicAdd(&lcur[b], 1);
    if (rank < CAP) {
      int2 q;
      q.x = ((r & (BROWS - 1)) << 17) | ecol[e];
      q.y = __float_as_int(eval_[e]);
      bpad[(long)b * CAP + rank] = q;
    }
  }
}

// ---------------------------------------------------------------------------
// agg3 (round-14): one block per bucket. bpad read ONCE into registers
// (<=6 int2/thread) and reused for hist + counting-sort. Aggregation is
// slot-vectorized: wave = 4 slots x 16 lanes; each quartet step processes
// 4 edges with ONE dwordx2 gather per lane (512 B/wave vs 128 B before),
// unroll x2 (8 edges, 2 loads in flight). Ragged tails handled by val=0
// masking (no remainder loop). Cross-slot shfl_xor reduce per row, then
// float4 store by slot-0 lanes.
// ---------------------------------------------------------------------------
__global__ __launch_bounds__(256) void agg2_kernel(
    const int* __restrict__ gcur, const int2* __restrict__ bpad,
    const u16* __restrict__ xwb, float* __restrict__ out) {
  __shared__ int2 dst[CAP];        // 12288 B
  __shared__ int  hist[BROWS];
  __shared__ int  lptr[BROWS + 1];
  __shared__ int  cur[BROWS];

  const int bucket = blockIdx.x;
  const int t = threadIdx.x;
  const int count = min(gcur[bucket], CAP);
  const long sbase = (long)bucket * CAP;

  if (t < BROWS) hist[t] = 0;
  __syncthreads();

  // single global read of this bucket's edges; cached in regs across phases
  int2 qr[6];                      // CAP = 6 * 256
  #pragma unroll
  for (int k = 0; k < 6; ++k) {
    const int e = t + k * 256;
    if (e < count) {
      qr[k] = bpad[sbase + e];
      atomicAdd(&hist[(qr[k].x >> 17) & (BROWS - 1)], 1);
    }
  }
  __syncthreads();

  if (t < 64) {
    const int v = hist[t];
    int s = v;
    #pragma unroll
    for (int o = 1; o < 64; o <<= 1) {
      const int u = __shfl_up(s, o);
      if (t >= o) s += u;
    }
    lptr[t + 1] = s;
    cur[t] = s - v;
    if (t == 0) lptr[0] = 0;
  }
  __syncthreads();

  #pragma unroll
  for (int k = 0; k < 6; ++k) {
    const int e = t + k * 256;
    if (e < count) {
      const int r = (qr[k].x >> 17) & (BROWS - 1);
      const int pos = atomicAdd(&cur[r], 1);
      dst[pos] = qr[k];
    }
  }
  __syncthreads();

  const int lane = t & 63;
  const int wave = t >> 6;
  const int slot = lane >> 4;      // 0..3  (edge sub-slot)
  const int li   = lane & 15;      // 0..15 (covers 4 cols each via dwordx2)
  const int row0 = bucket << BSHIFT;
  const int cmax = count - 1;      // count>=1 whenever any row has edges

  for (int r = wave; r < BROWS; r += 4) {
    const int row = row0 + r;
    if (row >= NN) break;
    const int s = lptr[r], en = lptr[r + 1];
    float a0 = 0.f, a1 = 0.f, a2 = 0.f, a3 = 0.f;
    for (int e = s; e < en; e += 8) {
      {
        const int idx = e + slot;
        const int2 q = dst[min(idx, cmax)];
        const float v = (idx < en) ? __int_as_float(q.y) : 0.f;
        const u32 col = (u32)q.x & 0x1FFFFu;
        const uint2 g = *reinterpret_cast<const uint2*>(
            xwb + (size_t)col * DOUT + li * 4);
        a0 = fmaf(v, __uint_as_float(g.x << 16), a0);
        a1 = fmaf(v, __uint_as_float(g.x & 0xFFFF0000u), a1);
        a2 = fmaf(v, __uint_as_float(g.y << 16), a2);
        a3 = fmaf(v, __uint_as_float(g.y & 0xFFFF0000u), a3);
      }
      {
        const int idx = e + 4 + slot;
        const int2 q = dst[min(idx, cmax)];
        const float v = (idx < en) ? __int_as_float(q.y) : 0.f;
        const u32 col = (u32)q.x & 0x1FFFFu;
        const uint2 g = *reinterpret_cast<const uint2*>(
            xwb + (size_t)col * DOUT + li * 4);
        a0 = fmaf(v, __uint_as_float(g.x << 16), a0);
        a1 = fmaf(v, __uint_as_float(g.x & 0xFFFF0000u), a1);
        a2 = fmaf(v, __uint_as_float(g.y << 16), a2);
        a3 = fmaf(v, __uint_as_float(g.y & 0xFFFF0000u), a3);
      }
    }
    // cross-slot reduce: all 4 slot copies of li end up holding the sum
    a0 += __shfl_xor(a0, 16); a0 += __shfl_xor(a0, 32);
    a1 += __shfl_xor(a1, 16); a1 += __shfl_xor(a1, 32);
    a2 += __shfl_xor(a2, 16); a2 += __shfl_xor(a2, 32);
    a3 += __shfl_xor(a3, 16); a3 += __shfl_xor(a3, 32);
    if (slot == 0) {
      float4 o;
      o.x = fmaxf(a0, 0.f); o.y = fmaxf(a1, 0.f);
      o.z = fmaxf(a2, 0.f); o.w = fmaxf(a3, 0.f);
      *reinterpret_cast<float4*>(&out[(size_t)row * DOUT + li * 4]) = o;
    }
  }
}

// ----------------------- fallback (atomic) path ----------------------------
__global__ __launch_bounds__(256) void scatter_kernel(
    const int* __restrict__ erow, const int* __restrict__ ecol,
    const float* __restrict__ eval_, const u16* __restrict__ xwb,
    float* __restrict__ out) {
  const int wave = (blockIdx.x * blockDim.x + threadIdx.x) >> 6;
  const int lane = threadIdx.x & 63;
  const int nwaves = (gridDim.x * blockDim.x) >> 6;
  const int per = (NE + nwaves - 1) / nwaves;
  const int e0 = wave * per;
  const int e1 = min(e0 + per, NE);
  for (int base = e0; base < e1; base += 64) {
    const int e = base + lane;
    int r = 0, c = 0; float v = 0.f;
    if (e < e1) { r = erow[e]; c = ecol[e]; v = eval_[e]; }
    const int cnt = min(64, e1 - base);
    for (int j = 0; j < cnt; ++j) {
      const int rj = __shfl(r, j);
      const int cj = __shfl(c, j);
      const float vj = __shfl(v, j);
      atomicAdd(&out[rj * DOUT + lane], vj * bf2f(xwb[cj * DOUT + lane]));
    }
  }
}

__global__ __launch_bounds__(256) void finish_kernel(float* __restrict__ out) {
  const int idx = (blockIdx.x * blockDim.x + threadIdx.x) * 4;
  if (idx < NN * DOUT) {
    float4 a = *reinterpret_cast<const float4*>(&out[idx]);
    a.x = fmaxf(a.x, 0.f); a.y = fmaxf(a.y, 0.f);
    a.z = fmaxf(a.z, 0.f); a.w = fmaxf(a.w, 0.f);
    *reinterpret_cast<float4*>(&out[idx]) = a;
  }
}

extern "C" void kernel_launch(void* const* d_in, const int* in_sizes, int n_in,
                              void* d_out, int out_size, void* d_ws, size_t ws_size,
                              hipStream_t stream) {
  const float* x     = (const float*)d_in[0];
  const int*   erow  = (const int*)d_in[1];
  const int*   ecol  = (const int*)d_in[2];
  const float* eval_ = (const float*)d_in[3];
  const float* w     = (const float*)d_in[4];
  float* out = (float*)d_out;

  char* ws = (char*)d_ws;
  u16* xwb = (u16*)(ws + XWB_B);

  const int gemm_grid = (NN + 63) / 64;   // 1563 blocks x 4 waves x 16 rows
  gemm_kernel<<<gemm_grid, 256, 0, stream>>>(x, w, xwb);

  if (ws_size >= (size_t)WS_NEED) {
    int*  gcur = (int*)(ws + GCUR_B);
    int2* bpad = (int2*)(ws + BPAD_B);

    hipMemsetAsync(gcur, 0, NB * 4, stream);
    const int place_grid = (NE + EPB - 1) / EPB;   // 196
    place_kernel<<<place_grid, 1024, 0, stream>>>(erow, ecol, eval_, gcur, bpad);
    agg2_kernel<<<NB, 256, 0, stream>>>(gcur, bpad, xwb, out);
  } else {
    hipMemsetAsync(d_out, 0, (size_t)NN * DOUT * sizeof(float), stream);
    scatter_kernel<<<2048, 256, 0, stream>>>(erow, ecol, eval_, xwb, out);
    const int fin_grid = (NN * DOUT / 4 + 255) / 256;
    finish_kernel<<<fin_grid, 256, 0, stream>>>(out);
  }
}